// Round 10
// baseline (246794.775 us; speedup 1.0000x reference)
//
#include <hip/hip_runtime.h>
#include <hip/hip_fp16.h>
#include <stdint.h>

// ---------------------------------------------------------------------------
// SequentialEMGPoseLSTM: 2-layer LSTM (H=256, B=64, T=4096) + LeakyReLU+Linear
//
// R12: K-split pairing. Post-mortem R11: step is ~90% VALU-issue-bound with
// v_dot2 at half rate (4cyc/wave64; fp16 vector peak == fp32 peak on CDNA).
// The only remaining lever is fewer dots per CU. The 128 near-idle GEMM CUs
// become K-partners:
//  - Chain (layer,b) is split: A-block owns k in [0,128) + state + tail;
//    B-block owns k in [128,256) and ships 1024 partial gate sums (4KB)
//    per step; A ships back h[128:256) (256B). Pairs (bid, bid+128) share
//    an XCD (128%8==0) -> exchange stays in one L2.
//  - Handshake: monotonic epochs, __hip_atomic acquire/release at agent
//    scope. A prologue flag=base+1; B step tt waits fA>=base+tt+1; B sets
//    fB=base+tt+2; A waits fB>=base+tt+2, tails, sets fA=base+tt+2.
//    Capped spins (1<<20) turn any protocol bug into fast-fail, not hang.
//  - All weights register-resident (8 rows x 16 u32 = 128/thread): the
//    135KB LDS weight array and its ~1500cyc/step streaming are gone.
//  - GEMM (xw1) moves into an all-256-blocks prologue phase: its input h1
//    is from the previous dispatch (same chunk schedule as before), so
//    correctness is unchanged; cost ~15-25us/dispatch.
//  - Flags zeroed by prep_kernel each launch (graph replays re-zero).
// ---------------------------------------------------------------------------

#define T_SEQ 4096
#define NB    64
#define HID   256
#define G4    1024
#define INCH  16
#define OC    20

typedef _Float16 h2v   __attribute__((ext_vector_type(2)));
typedef _Float16 f16x8 __attribute__((ext_vector_type(8)));
typedef float    f32x4 __attribute__((ext_vector_type(4)));

__device__ __forceinline__ float fdot2(uint32_t a, uint32_t b, float c) {
  return __builtin_amdgcn_fdot2(__builtin_bit_cast(h2v, a),
                                __builtin_bit_cast(h2v, b), c, false);
}
__device__ __forceinline__ float sigf(float x) {
  x = fminf(fmaxf(x, -30.f), 30.f);
  return 1.f / (1.f + __expf(-x));
}
__device__ __forceinline__ float tanhf_fast(float x) {
  x = fminf(fmaxf(x, -15.f), 15.f);
  float e = __expf(-2.f * x);
  return (1.f - e) / (1.f + e);
}
// Sum across the 4 slices of a quad (lane bits 0-1) on the VALU pipe.
__device__ __forceinline__ float quad_sum(float a) {
  a += __int_as_float(
      __builtin_amdgcn_update_dpp(0, __float_as_int(a), 0xB1, 0xF, 0xF, true));
  a += __int_as_float(
      __builtin_amdgcn_update_dpp(0, __float_as_int(a), 0x4E, 0xF, 0xF, true));
  return a;
}
// Capped acquire-spin: protocol bug -> wrong answer fast, never a hang.
__device__ __forceinline__ void spin_ge(uint32_t* f, uint32_t e) {
  uint32_t n = 0;
  while (__hip_atomic_load(f, __ATOMIC_ACQUIRE, __HIP_MEMORY_SCOPE_AGENT) < e)
    if (++n > (1u << 20)) break;
}
__device__ __forceinline__ void flag_set(uint32_t* f, uint32_t e) {
  __hip_atomic_store(f, e, __ATOMIC_RELEASE, __HIP_MEMORY_SCOPE_AGENT);
}
#define PIN(x) asm volatile("" : "+v"(x))

// LDS: small now (weights fully in registers).
//  hbufA: h[0:128) f16 double buffer (A-blocks).
//  u.xb : layer0 packed x pairs; u.h1: head weights + leaky buffer (layer1).
struct SmemR {
  uint32_t hbufA[2][64];      // 512 B
  union {
    uint32_t xb[512 * 8];     // 16 KB (Tc<=512)
    struct {
      __half abuf[2][320];
      __half whd[20 * 264];
      float  bh[20];
    } h1;
  } u;
};
struct SmemG {
  __half a[128 * 40];
  __half b[64 * 40];
};
union Smem { SmemR r; SmemG g; };

struct Params {
  const float* x;
  const __half *wh0, *wh1, *wi0, *wi1, *whd;
  const float  *bs0, *bs1, *bhd;
  float *h0s, *c0s, *h1s, *c1s;
  __half* h1w; const __half* h1r;
  float* xww;  const float* xwr;
  float* pbox;     // [128 pairs][1024] f32 partial gate sums (B -> A)
  __half* hbox;    // [128 pairs][128]  f16 h[128:256)        (A -> B)
  uint32_t *fA, *fB;  // [128] epoch flags
  float* y;
  int L, Tc, nch;
};

// ---------------------------------------------------------------------------
// GEMM phase (all 256 blocks): xw1[tb,g] = sum_k h1[tb,k]*Wih1[g,k].
// Same tile as R3; each block loops tiles vt = bid, bid+256, ...
// Input h1r is from the previous dispatch -> complete. ~Tc/32 tiles/block.
// ---------------------------------------------------------------------------
__device__ void gemm_phase(SmemG& S, int chG, const Params& P) {
  if (chG < 0 || chG >= P.nch) return;
  const int ntile = P.Tc * 8;
  const int tid = threadIdx.x, lane = tid & 63, w = tid >> 6;
  const int wm = w & 3, wn = w >> 2;
  for (int vt = blockIdx.x; vt < ntile; vt += 256) {
    const int nt = vt & 15, mt = vt >> 4;
    const int tb0 = mt * 128, g0 = nt * 64;
    f32x4 cacc[2][2] = {};
    for (int kk = 0; kk < 256; kk += 32) {
      __syncthreads();
      {
        int row = tid >> 2, q = tid & 3;
        *(uint4*)&S.a[row * 40 + q * 8] =
            *(const uint4*)(P.h1r + (size_t)(tb0 + row) * 256 + kk + q * 8);
      }
      if (tid < 256) {
        int row = tid >> 2, q = tid & 3;
        *(uint4*)&S.b[row * 40 + q * 8] =
            *(const uint4*)(P.wi1 + (size_t)(g0 + row) * 256 + kk + q * 8);
      }
      __syncthreads();
      f16x8 af[2], bf[2];
#pragma unroll
      for (int mi = 0; mi < 2; mi++)
        af[mi] = *(const f16x8*)&S.a[(wm * 32 + mi * 16 + (lane & 15)) * 40 + (lane >> 4) * 8];
#pragma unroll
      for (int ni = 0; ni < 2; ni++)
        bf[ni] = *(const f16x8*)&S.b[(wn * 32 + ni * 16 + (lane & 15)) * 40 + (lane >> 4) * 8];
#pragma unroll
      for (int mi = 0; mi < 2; mi++)
#pragma unroll
        for (int ni = 0; ni < 2; ni++)
          cacc[mi][ni] = __builtin_amdgcn_mfma_f32_16x16x32_f16(af[mi], bf[ni], cacc[mi][ni], 0, 0, 0);
    }
#pragma unroll
    for (int mi = 0; mi < 2; mi++)
#pragma unroll
      for (int ni = 0; ni < 2; ni++) {
        int m = wm * 32 + mi * 16 + (lane >> 4) * 4;
        int n = g0 + wn * 32 + ni * 16 + (lane & 15);
#pragma unroll
        for (int r = 0; r < 4; r++)
          P.xww[(size_t)(tb0 + m + r) * G4 + n] = cacc[mi][ni][r];
      }
  }
}

// ---------------------------------------------------------------------------
// A-role: k in [0,128). 512 threads: slice=tid&3 (32 halves), rg=tid>>2.
// Rows rg+128j, j=0..7, all weights in regs. Owners (slice<2) keep state,
// apply tail with B's partials, publish h[128:256) to hbox.
// ---------------------------------------------------------------------------
template <int LAYER>
__device__ void role_recA(SmemR& S, int ch, const Params& P, int b) {
  if (ch < 0 || ch >= P.nch) return;
  const int tid = threadIdx.x, slice = tid & 3, rg = tid >> 2, Tc = P.Tc;
  const __half* whh = (LAYER == 0) ? P.wh0 : P.wh1;
  const int pid = LAYER * 64 + b;
  const int t0 = ch * Tc;
  const uint32_t base = (uint32_t)(P.L * Tc);

  if (LAYER == 0) {
    for (int i = tid; i < Tc * 8; i += 512) {
      int dp = i / Tc, tt = i - dp * Tc;
      float v0 = P.x[(b * INCH + 2 * dp) * T_SEQ + t0 + tt];
      float v1 = P.x[(b * INCH + 2 * dp + 1) * T_SEQ + t0 + tt];
      uint32_t pv = (uint32_t)__half_as_ushort(__float2half(v0)) |
                    ((uint32_t)__half_as_ushort(__float2half(v1)) << 16);
      S.u.xb[tt * 8 + dp] = pv;
    }
  } else {
    for (int i = tid; i < OC * 256; i += 512) {
      int o = i >> 8, k = i & 255;
      S.u.h1.whd[o * 264 + k] = P.whd[i];
    }
    if (tid < OC) S.u.h1.bh[tid] = P.bhd[tid];
  }

  // Weights: rows rg+128j, k-slice [32*slice, 32*slice+32). 16 u32/row.
  uint32_t wr[8][16];
#pragma unroll
  for (int j = 0; j < 8; ++j) {
    const uint4* p = (const uint4*)(whh + (rg + 128 * j) * 256 + slice * 32);
#pragma unroll
    for (int q = 0; q < 4; ++q) {
      uint4 v = p[q];
      wr[j][4 * q] = v.x; wr[j][4 * q + 1] = v.y;
      wr[j][4 * q + 2] = v.z; wr[j][4 * q + 3] = v.w;
    }
  }
#pragma unroll
  for (int j = 0; j < 8; ++j)
#pragma unroll
    for (int q = 0; q < 16; ++q) PIN(wr[j][q]);

  uint32_t wx[8][2];
  if (LAYER == 0) {
#pragma unroll
    for (int j = 0; j < 8; j++) {
      const uint32_t* p = (const uint32_t*)(P.wi0 + (rg + 128 * j) * INCH + slice * 4);
      wx[j][0] = p[0]; wx[j][1] = p[1];
    }
#pragma unroll
    for (int j = 0; j < 8; j++) { PIN(wx[j][0]); PIN(wx[j][1]); }
  }

  const bool own = (slice < 2);
  const int chn = rg + ((slice & 1) << 7);
  float* hs = (LAYER == 0) ? P.h0s : P.h1s;
  float* cs = (LAYER == 0) ? P.c0s : P.c1s;
  float bs4[4] = {0.f, 0.f, 0.f, 0.f};
  float hO = 0.f, cO = 0.f;
  if (own) {
    const float* bsg = (LAYER == 0) ? P.bs0 : P.bs1;
#pragma unroll
    for (int k = 0; k < 4; k++) bs4[k] = bsg[chn + 256 * k];
    if (ch != 0) { hO = hs[b * 256 + chn]; cO = cs[b * 256 + chn]; }
    __half h16 = __float2half(hO);
    if (slice == 0) ((__half*)S.hbufA[0])[chn] = h16;
    else            P.hbox[(size_t)pid * 128 + (chn - 128)] = h16;
  }
  const float* xp = (LAYER == 1 && own) ? (P.xwr + (size_t)b * G4 + chn)
                                        : (const float*)nullptr;
  __syncthreads();                       // drains hbox init stores too
  if (tid == 0) flag_set(&P.fA[pid], base + 1);

  const float* pb = P.pbox + (size_t)pid * 1024;
  __half hprev = __float2half(0.f);

  for (int tt = 0; tt < Tc; ++tt) {
    // Post-barrier zone: these retire under the dot phase.
    if (LAYER == 0 && own && tt > 0)
      P.h1w[(size_t)((tt - 1) * NB + b) * 256 + chn] = hprev;
    float xwv[4] = {0.f, 0.f, 0.f, 0.f};
    if (LAYER == 1 && own) {
      const float* q = xp + (size_t)tt * (NB * G4);
      xwv[0] = q[0]; xwv[1] = q[256]; xwv[2] = q[512]; xwv[3] = q[768];
    }

    const uint4* hp = (const uint4*)((const __half*)S.hbufA[tt & 1] + slice * 32);
    uint32_t hh[16];
    { uint4 v0 = hp[0], v1 = hp[1], v2 = hp[2], v3 = hp[3];
      hh[0]=v0.x; hh[1]=v0.y; hh[2]=v0.z; hh[3]=v0.w;
      hh[4]=v1.x; hh[5]=v1.y; hh[6]=v1.z; hh[7]=v1.w;
      hh[8]=v2.x; hh[9]=v2.y; hh[10]=v2.z; hh[11]=v2.w;
      hh[12]=v3.x; hh[13]=v3.y; hh[14]=v3.z; hh[15]=v3.w; }
    float acc[8];
#pragma unroll
    for (int j = 0; j < 8; ++j) acc[j] = 0.f;
#pragma unroll
    for (int j = 0; j < 8; ++j) {
      float a = acc[j];
#pragma unroll
      for (int q = 0; q < 16; ++q) a = fdot2(wr[j][q], hh[q], a);
      acc[j] = a;
    }
    if (LAYER == 0) {
      uint32_t xv0 = S.u.xb[tt * 8 + 2 * slice];
      uint32_t xv1 = S.u.xb[tt * 8 + 2 * slice + 1];
#pragma unroll
      for (int j = 0; j < 8; j++) {
        acc[j] = fdot2(wx[j][0], xv0, acc[j]);
        acc[j] = fdot2(wx[j][1], xv1, acc[j]);
      }
    }
#pragma unroll
    for (int j = 0; j < 8; j++) acc[j] = quad_sum(acc[j]);

    // Partner partials (k in [128,256)) for this step.
    spin_ge(&P.fB[pid], base + tt + 2);

    if (own) {
      const int o = slice & 1;
      float4 pv = ((const float4*)pb)[chn];
      float gi = acc[0 + o] + bs4[0] + pv.x;
      float gf = acc[2 + o] + bs4[1] + pv.y;
      float gg = acc[4 + o] + bs4[2] + pv.z;
      float go = acc[6 + o] + bs4[3] + pv.w;
      if (LAYER == 1) { gi += xwv[0]; gf += xwv[1]; gg += xwv[2]; go += xwv[3]; }
      float iv = sigf(gi), fv = sigf(gf);
      float gv = tanhf_fast(gg), ov = sigf(go);
      cO = fv * cO + iv * gv;
      hO = ov * tanhf_fast(cO);
      __half h16 = __float2half(hO);
      if (slice == 0) ((__half*)S.hbufA[(tt + 1) & 1])[chn] = h16;
      else            P.hbox[(size_t)pid * 128 + (chn - 128)] = h16;
      if (LAYER == 0) {
        hprev = h16;
      } else {
        float av = hO > 0.f ? hO : 0.01f * hO;
        S.u.h1.abuf[tt & 1][(chn >> 5) * 40 + (chn & 31)] = __float2half(av);
      }
    }
    __syncthreads();  // drains hbox stores (vmcnt) + hbufA (lgkm)
    if (tid == 0) flag_set(&P.fA[pid], base + tt + 2);

    // Head (layer1): reads abuf[tt&1]; next overwrite 2 barriers away.
    if (LAYER == 1 && tid < OC * 8) {
      int o = tid >> 3, ks = tid & 7;
      const uint4* wp = (const uint4*)&S.u.h1.whd[o * 264 + ks * 32];
      const uint4* ap = (const uint4*)&S.u.h1.abuf[tt & 1][ks * 40];
      float a = 0.f;
#pragma unroll
      for (int q = 0; q < 4; q++) {
        uint4 w4 = wp[q];
        uint4 a4 = ap[q];
        a = fdot2(w4.x, a4.x, a);
        a = fdot2(w4.y, a4.y, a);
        a = fdot2(w4.z, a4.z, a);
        a = fdot2(w4.w, a4.w, a);
      }
      a += __shfl_xor(a, 1);
      a += __shfl_xor(a, 2);
      a += __shfl_xor(a, 4);
      if (ks == 0) P.y[(b * OC + o) * T_SEQ + t0 + tt] = a + S.u.h1.bh[o];
    }
  }
  if (own) {
    if (LAYER == 0)
      P.h1w[(size_t)((Tc - 1) * NB + b) * 256 + chn] = hprev;
    hs[b * 256 + chn] = hO;
    cs[b * 256 + chn] = cO;
  }
}

// ---------------------------------------------------------------------------
// B-role: k in [128,256). Reads h-half from hbox (global, L2-shared with
// partner), computes partial gate sums, ships them via pbox. No state.
// ---------------------------------------------------------------------------
template <int LAYER>
__device__ void role_recB(int ch, const Params& P, int b) {
  if (ch < 0 || ch >= P.nch) return;
  const int tid = threadIdx.x, slice = tid & 3, rg = tid >> 2, Tc = P.Tc;
  const __half* whh = (LAYER == 0) ? P.wh0 : P.wh1;
  const int pid = LAYER * 64 + b;
  const uint32_t base = (uint32_t)(P.L * Tc);

  uint32_t wr[8][16];
#pragma unroll
  for (int j = 0; j < 8; ++j) {
    const uint4* p = (const uint4*)(whh + (rg + 128 * j) * 256 + 128 + slice * 32);
#pragma unroll
    for (int q = 0; q < 4; ++q) {
      uint4 v = p[q];
      wr[j][4 * q] = v.x; wr[j][4 * q + 1] = v.y;
      wr[j][4 * q + 2] = v.z; wr[j][4 * q + 3] = v.w;
    }
  }
#pragma unroll
  for (int j = 0; j < 8; ++j)
#pragma unroll
    for (int q = 0; q < 16; ++q) PIN(wr[j][q]);

  const bool own = (slice < 2);
  const int chn = rg + ((slice & 1) << 7);
  const __half* hb = P.hbox + (size_t)pid * 128;
  float* pb = P.pbox + (size_t)pid * 1024;

  for (int tt = 0; tt < Tc; ++tt) {
    // Wait for partner's h (tt==0: prologue init; else step tt-1's tail).
    spin_ge(&P.fA[pid], base + tt + 1);
    const uint4* hp = (const uint4*)(hb + slice * 32);
    uint32_t hh[16];
    { uint4 v0 = hp[0], v1 = hp[1], v2 = hp[2], v3 = hp[3];
      hh[0]=v0.x; hh[1]=v0.y; hh[2]=v0.z; hh[3]=v0.w;
      hh[4]=v1.x; hh[5]=v1.y; hh[6]=v1.z; hh[7]=v1.w;
      hh[8]=v2.x; hh[9]=v2.y; hh[10]=v2.z; hh[11]=v2.w;
      hh[12]=v3.x; hh[13]=v3.y; hh[14]=v3.z; hh[15]=v3.w; }
    float acc[8];
#pragma unroll
    for (int j = 0; j < 8; ++j) acc[j] = 0.f;
#pragma unroll
    for (int j = 0; j < 8; ++j) {
      float a = acc[j];
#pragma unroll
      for (int q = 0; q < 16; ++q) a = fdot2(wr[j][q], hh[q], a);
      acc[j] = a;
    }
#pragma unroll
    for (int j = 0; j < 8; j++) acc[j] = quad_sum(acc[j]);
    if (own) {
      const int o = slice & 1;
      float4 pv;
      pv.x = acc[0 + o]; pv.y = acc[2 + o];
      pv.z = acc[4 + o]; pv.w = acc[6 + o];
      ((float4*)pb)[chn] = pv;
    }
    __syncthreads();  // vmcnt drain: all waves' partial stores complete
    if (tid == 0) flag_set(&P.fB[pid], base + tt + 2);
  }
}

__global__ __launch_bounds__(512)
__attribute__((amdgpu_waves_per_eu(2, 2)))
void fused_kernel(Params P) {
  __shared__ Smem S;
  const int bid = blockIdx.x;
  // Phase 1: GEMM for chunk L-1 (input from previous dispatch), all blocks.
  gemm_phase(S.g, P.L - 1, P);
  __syncthreads();
  // Phase 2: recurrent pairs. A = bid, B = bid+128 (same XCD: 128%8==0).
  if (bid < 64)        role_recA<0>(S.r, P.L,     P, bid);
  else if (bid < 128)  role_recA<1>(S.r, P.L - 2, P, bid - 64);
  else if (bid < 192)  role_recB<0>(P.L,     P, bid - 128);
  else                 role_recB<1>(P.L - 2, P, bid - 192);
}

// ---------------------------------------------------------------------------
__global__ void prep_kernel(const float* Wih0, const float* Whh0,
                            const float* bih0, const float* bhh0,
                            const float* Wih1, const float* Whh1,
                            const float* bih1, const float* bhh1,
                            const float* Whead, const float* bhead,
                            __half* wh0, __half* wh1, __half* wi1, __half* wi0,
                            __half* whd, float* bs0, float* bs1, float* bhd,
                            uint32_t* fA, uint32_t* fB) {
  int i = blockIdx.x * blockDim.x + threadIdx.x;
  if (i < G4 * HID) {
    wh0[i] = __float2half(Whh0[i]);
    wh1[i] = __float2half(Whh1[i]);
    wi1[i] = __float2half(Wih1[i]);
  }
  if (i < G4 * INCH) wi0[i] = __float2half(Wih0[i]);
  if (i < OC * HID)  whd[i] = __float2half(Whead[i]);
  if (i < G4) { bs0[i] = bih0[i] + bhh0[i]; bs1[i] = bih1[i] + bhh1[i]; }
  if (i < OC) bhd[i] = bhead[i];
  if (i < 128) { fA[i] = 0; fB[i] = 0; }   // epochs restart each launch/replay
}

// ---------------------------------------------------------------------------
extern "C" void kernel_launch(void* const* d_in, const int* in_sizes, int n_in,
                              void* d_out, int out_size, void* d_ws, size_t ws_size,
                              hipStream_t stream) {
  const float* x     = (const float*)d_in[0];
  const float* Wih0  = (const float*)d_in[1];
  const float* Whh0  = (const float*)d_in[2];
  const float* bih0  = (const float*)d_in[3];
  const float* bhh0  = (const float*)d_in[4];
  const float* Wih1  = (const float*)d_in[5];
  const float* Whh1  = (const float*)d_in[6];
  const float* bih1  = (const float*)d_in[7];
  const float* bhh1  = (const float*)d_in[8];
  const float* Whead = (const float*)d_in[9];
  const float* bhead = (const float*)d_in[10];
  float* y = (float*)d_out;

  char* ws = (char*)d_ws;
  size_t cur = 0;
  auto alloc = [&](size_t sz) -> char* {
    char* p = ws + cur;
    cur = (cur + sz + 255) & ~(size_t)255;
    return p;
  };
  __half* wh0 = (__half*)alloc(G4 * HID * 2);
  __half* wh1 = (__half*)alloc(G4 * HID * 2);
  __half* wi1 = (__half*)alloc(G4 * HID * 2);
  __half* wi0 = (__half*)alloc(G4 * INCH * 2);
  __half* whd = (__half*)alloc(OC * HID * 2);
  float* bs0 = (float*)alloc(G4 * 4);
  float* bs1 = (float*)alloc(G4 * 4);
  float* bhd = (float*)alloc(OC * 4);
  float* h0s = (float*)alloc(NB * HID * 4);
  float* c0s = (float*)alloc(NB * HID * 4);
  float* h1s = (float*)alloc(NB * HID * 4);
  float* c1s = (float*)alloc(NB * HID * 4);
  float* pbox = (float*)alloc(128 * 1024 * 4);
  __half* hbox = (__half*)alloc(128 * 128 * 2);
  uint32_t* fA = (uint32_t*)alloc(128 * 4);
  uint32_t* fB = (uint32_t*)alloc(128 * 4);
  size_t fixed = cur;

  int Tc = 256;
  while (Tc > 64) {
    size_t need = fixed + 2 * ((size_t)Tc * NB * HID * 2 + 512) +
                  2 * ((size_t)Tc * NB * G4 * 4 + 512);
    if (need <= ws_size) break;
    Tc >>= 1;
  }
  __half* h1buf[2];
  float* xwbuf[2];
  h1buf[0] = (__half*)alloc((size_t)Tc * NB * HID * 2);
  h1buf[1] = (__half*)alloc((size_t)Tc * NB * HID * 2);
  xwbuf[0] = (float*)alloc((size_t)Tc * NB * G4 * 4);
  xwbuf[1] = (float*)alloc((size_t)Tc * NB * G4 * 4);

  const int nch = T_SEQ / Tc;

  prep_kernel<<<(G4 * HID + 255) / 256, 256, 0, stream>>>(
      Wih0, Whh0, bih0, bhh0, Wih1, Whh1, bih1, bhh1, Whead, bhead,
      wh0, wh1, wi1, wi0, whd, bs0, bs1, bhd, fA, fB);

  for (int L = 0; L < nch + 2; ++L) {
    Params P;
    P.x = x;
    P.wh0 = wh0; P.wh1 = wh1; P.wi0 = wi0; P.wi1 = wi1; P.whd = whd;
    P.bs0 = bs0; P.bs1 = bs1; P.bhd = bhd;
    P.h0s = h0s; P.c0s = c0s; P.h1s = h1s; P.c1s = c1s;
    P.h1w = h1buf[L & 1];
    P.h1r = h1buf[(L + 1) & 1];
    P.xww = xwbuf[(L + 1) & 1];
    P.xwr = xwbuf[L & 1];
    P.pbox = pbox; P.hbox = hbox; P.fA = fA; P.fB = fB;
    P.y = y;
    P.L = L; P.Tc = Tc; P.nch = nch;
    fused_kernel<<<256, 512, 0, stream>>>(P);
  }
}